// Round 3
// baseline (26.996 us; speedup 1.0000x reference)
//
#include <hip/hip_runtime.h>

#define NQ 8

__global__ __launch_bounds__(256) void acrobot_kernel(
    const float* __restrict__ qg, const float* __restrict__ vg,
    const float* __restrict__ ug, const float* __restrict__ pg,
    float* __restrict__ outg, int B)
{
    const int b = blockIdx.x * blockDim.x + threadIdx.x;
    if (b >= B) return;

    // ---- per-sample loads first (issue early; 2 dwordx4 each, coalesced) ----
    const float4* q4 = reinterpret_cast<const float4*>(qg) + (size_t)b * 2;
    const float4* v4 = reinterpret_cast<const float4*>(vg) + (size_t)b * 2;
    const float4* u4 = reinterpret_cast<const float4*>(ug) + (size_t)b * 2;
    float4 qa = q4[0], qb = q4[1];
    float4 va = v4[0], vb = v4[1];
    float4 ua = u4[0], ub = u4[1];

    // ---- uniform params (constant indices -> s_load) ----
    float ms[NQ], ls[NQ], taus[NQ];
#pragma unroll
    for (int i = 0; i < NQ; i++) ms[i] = pg[i];
#pragma unroll
    for (int i = 0; i < NQ; i++) ls[i] = pg[NQ + i];
    const float grav = pg[2 * NQ];
#pragma unroll
    for (int i = 0; i < NQ; i++) taus[i] = pg[2 * NQ + 1 + i];

    // suffix sums: ms_suf[i] = sum_{k>=i} ms[k]; Is_suf likewise for ms*ls^2/12
    float ms_suf[NQ], Is_suf[NQ];
    {
        float accm = 0.f, acci = 0.f;
#pragma unroll
        for (int i = NQ - 1; i >= 0; i--) {
            accm += ms[i];
            acci += ms[i] * ls[i] * ls[i] * (1.0f / 12.0f);
            ms_suf[i] = accm;
            Is_suf[i] = acci;
        }
    }
    float lcoef[NQ], Dd[NQ], gcoef[NQ];
#pragma unroll
    for (int i = 0; i < NQ; i++) {
        float coefA = ms_suf[i] - 0.5f * ms[i];
        lcoef[i] = ls[i] * coefA;                       // A[i][j] = ls[i] * lcoef[j] (j = max)
        Dd[i]    = ls[i] * ls[i] * (ms_suf[i] - 0.75f * ms[i]) + Is_suf[i];
        gcoef[i] = grav * ls[i] * coefA;
    }

    float q[NQ] = {qa.x, qa.y, qa.z, qa.w, qb.x, qb.y, qb.z, qb.w};
    float v[NQ] = {va.x, va.y, va.z, va.w, vb.x, vb.y, vb.z, vb.w};
    float u[NQ] = {ua.x, ua.y, ua.z, ua.w, ub.x, ub.y, ub.z, ub.w};

    // cumsum of q; sincos of each partial sum
    float cs[NQ];
    cs[0] = q[0];
#pragma unroll
    for (int i = 1; i < NQ; i++) cs[i] = cs[i - 1] + q[i];
    float sn[NQ], cn[NQ];
#pragma unroll
    for (int i = 0; i < NQ; i++) __sincosf(cs[i], &sn[i], &cn[i]);

    // cumsum of v; vv = v .* Vc
    float Vc[NQ];
    Vc[0] = v[0];
#pragma unroll
    for (int i = 1; i < NQ; i++) Vc[i] = Vc[i - 1] + v[i];
    float vv[NQ];
#pragma unroll
    for (int i = 0; i < NQ; i++) vv[i] = v[i] * Vc[i];

    // ---- build lower triangle of M; accumulate w = S*v, z = S*vv in pair loop
    // S[i][j] = A[i][j]*sin(cs_i - cs_j), antisymmetric.
    float T[NQ][NQ];   // lower triangle only (upper elements dead -> SROA'd away)
    float w[NQ], z[NQ];
#pragma unroll
    for (int i = 0; i < NQ; i++) { w[i] = 0.f; z[i] = 0.f; T[i][i] = Dd[i]; }
#pragma unroll
    for (int i = 0; i < NQ; i++) {
#pragma unroll
        for (int j = i + 1; j < NQ; j++) {
            float a  = ls[i] * lcoef[j];               // A[i][j], max = j
            float cd = cn[i] * cn[j] + sn[i] * sn[j];  // cos(cs_i - cs_j)
            float sd = sn[i] * cn[j] - cn[i] * sn[j];  // sin(cs_i - cs_j)
            T[j][i]  = a * cd + Is_suf[j];             // M[i][j] == M[j][i]
            float sij = a * sd;                        // S[i][j]; S[j][i] = -sij
            w[i] += sij * v[j];  w[j] -= sij * v[i];
            z[i] += sij * vv[j]; z[j] -= sij * vv[i];
        }
    }

    // suffix sum of v[i]*w[i]; gravity gradient suffix sum
    float sufvw[NQ], G[NQ];
    {
        float acc = 0.f, accg = 0.f;
#pragma unroll
        for (int i = NQ - 1; i >= 0; i--) {
            acc  += v[i] * w[i];     sufvw[i] = acc;
            accg += gcoef[i] * sn[i]; G[i] = accg;
        }
    }

    // rhs = taus*u - Cv - G;  Cv[k] = -Vc[k]*w[k] + z[k] + sufvw[k]
    float rhs[NQ];
#pragma unroll
    for (int k = 0; k < NQ; k++) {
        float Cv = -Vc[k] * w[k] + z[k] + sufvw[k];
        rhs[k] = taus[k] * u[k] - Cv - G[k];
    }

    // ---- right-looking Cholesky, in registers; diag holds 1/sqrt(d) ----
#pragma unroll
    for (int j = 0; j < NQ; j++) {
        float rinv = __builtin_amdgcn_rsqf(T[j][j]);   // v_rsq_f32
        T[j][j] = rinv;
#pragma unroll
        for (int i = j + 1; i < NQ; i++) T[i][j] *= rinv;
#pragma unroll
        for (int k = j + 1; k < NQ; k++)
#pragma unroll
            for (int i = k; i < NQ; i++) T[i][k] -= T[i][j] * T[k][j];
    }
    // forward: L y = rhs
    float y[NQ];
#pragma unroll
    for (int i = 0; i < NQ; i++) {
        float s = rhs[i];
#pragma unroll
        for (int t = 0; t < i; t++) s -= T[i][t] * y[t];
        y[i] = s * T[i][i];
    }
    // backward: L^T x = y
    float x[NQ];
#pragma unroll
    for (int i = NQ - 1; i >= 0; i--) {
        float s = y[i];
#pragma unroll
        for (int t = i + 1; t < NQ; t++) s -= T[t][i] * x[t];
        x[i] = s * T[i][i];
    }

    float4* o4 = reinterpret_cast<float4*>(outg) + (size_t)b * 2;
    o4[0] = make_float4(x[0], x[1], x[2], x[3]);
    o4[1] = make_float4(x[4], x[5], x[6], x[7]);
}

extern "C" void kernel_launch(void* const* d_in, const int* in_sizes, int n_in,
                              void* d_out, int out_size, void* d_ws, size_t ws_size,
                              hipStream_t stream) {
    const float* q = (const float*)d_in[0];
    const float* v = (const float*)d_in[1];
    const float* u = (const float*)d_in[2];
    const float* p = (const float*)d_in[3];
    float* out = (float*)d_out;
    int B = in_sizes[0] / NQ;
    const int threads = 256;
    int blocks = (B + threads - 1) / threads;

    // MEASUREMENT ROUND: launch the identical kernel 5x in one graph.
    // dur = OH + 5*K  vs round-2's  dur = OH + K  ->  K = (dur3 - dur2)/4.
    // First 4 launches write to scratch (d_ws, >= 4 MB), final writes d_out.
    // Deterministic: d_out written exactly once per kernel_launch call.
    float* scratch = (float*)d_ws;
    for (int r = 0; r < 5; r++) {
        float* dst = (r == 4) ? out : scratch;
        acrobot_kernel<<<blocks, threads, 0, stream>>>(q, v, u, p, dst, B);
    }
}

// Round 4
// 18.861 us; speedup vs baseline: 1.4313x; 1.4313x over previous
//
#include <hip/hip_runtime.h>

#define NQ 8

__global__ __launch_bounds__(256) void acrobot_kernel(
    const float* __restrict__ qg, const float* __restrict__ vg,
    const float* __restrict__ ug, const float* __restrict__ pg,
    float* __restrict__ outg, int B)
{
    const int b = blockIdx.x * blockDim.x + threadIdx.x;
    if (b >= B) return;

    // ---- per-sample loads first (issue early; 2 dwordx4 each, coalesced) ----
    const float4* q4 = reinterpret_cast<const float4*>(qg) + (size_t)b * 2;
    const float4* v4 = reinterpret_cast<const float4*>(vg) + (size_t)b * 2;
    const float4* u4 = reinterpret_cast<const float4*>(ug) + (size_t)b * 2;
    float4 qa = q4[0], qb = q4[1];
    float4 va = v4[0], vb = v4[1];
    float4 ua = u4[0], ub = u4[1];

    // ---- uniform params (constant indices -> scalar loads) ----
    float ms[NQ], ls[NQ], taus[NQ];
#pragma unroll
    for (int i = 0; i < NQ; i++) ms[i] = pg[i];
#pragma unroll
    for (int i = 0; i < NQ; i++) ls[i] = pg[NQ + i];
    const float grav = pg[2 * NQ];
#pragma unroll
    for (int i = 0; i < NQ; i++) taus[i] = pg[2 * NQ + 1 + i];

    // suffix sums: ms_suf[i] = sum_{k>=i} ms[k]; Is_suf likewise for ms*ls^2/12
    float ms_suf[NQ], Is_suf[NQ];
    {
        float accm = 0.f, acci = 0.f;
#pragma unroll
        for (int i = NQ - 1; i >= 0; i--) {
            accm += ms[i];
            acci += ms[i] * ls[i] * ls[i] * (1.0f / 12.0f);
            ms_suf[i] = accm;
            Is_suf[i] = acci;
        }
    }
    float lcoef[NQ], Dd[NQ], gcoef[NQ];
#pragma unroll
    for (int i = 0; i < NQ; i++) {
        float coefA = ms_suf[i] - 0.5f * ms[i];
        lcoef[i] = ls[i] * coefA;                       // A[i][j] = ls[i] * lcoef[j] (j = max)
        Dd[i]    = ls[i] * ls[i] * (ms_suf[i] - 0.75f * ms[i]) + Is_suf[i];
        gcoef[i] = grav * ls[i] * coefA;
    }

    float q[NQ] = {qa.x, qa.y, qa.z, qa.w, qb.x, qb.y, qb.z, qb.w};
    float v[NQ] = {va.x, va.y, va.z, va.w, vb.x, vb.y, vb.z, vb.w};
    float u[NQ] = {ua.x, ua.y, ua.z, ua.w, ub.x, ub.y, ub.z, ub.w};

    // cumsum of q; native-HW sincos of each partial sum.
    // v_sin/v_cos take REVOLUTIONS: r = x/(2pi), fract to [0,1). |cs| <~ 15 rad
    // so float precision of r is ~6e-7 rad -- far inside the absmax slack.
    float cs[NQ];
    cs[0] = q[0];
#pragma unroll
    for (int i = 1; i < NQ; i++) cs[i] = cs[i - 1] + q[i];
    float sn[NQ], cn[NQ];
#pragma unroll
    for (int i = 0; i < NQ; i++) {
        float r = cs[i] * 0.15915494309189535f;   // 1/(2*pi)
        r = r - floorf(r);                        // v_fract path
        sn[i] = __builtin_amdgcn_sinf(r);         // v_sin_f32
        cn[i] = __builtin_amdgcn_cosf(r);         // v_cos_f32
    }

    // cumsum of v; vv = v .* Vc
    float Vc[NQ];
    Vc[0] = v[0];
#pragma unroll
    for (int i = 1; i < NQ; i++) Vc[i] = Vc[i - 1] + v[i];
    float vv[NQ];
#pragma unroll
    for (int i = 0; i < NQ; i++) vv[i] = v[i] * Vc[i];

    // pre-scale ls_i into the trig values: sl = ls*sn, cl = ls*cn
    float sl[NQ], cl[NQ];
#pragma unroll
    for (int i = 0; i < NQ; i++) { sl[i] = ls[i] * sn[i]; cl[i] = ls[i] * cn[i]; }

    // ---- build lower triangle of M; accumulate w = S*v, z = S*vv in pair loop
    // S[i][j] = A[i][j]*sin(cs_i - cs_j), antisymmetric. A[i][j] = ls_i*lcoef_j (j>i).
    float T[NQ][NQ];   // lower triangle only (upper elements dead -> SROA'd away)
    float w[NQ], z[NQ];
#pragma unroll
    for (int i = 0; i < NQ; i++) { w[i] = 0.f; z[i] = 0.f; T[i][i] = Dd[i]; }
#pragma unroll
    for (int i = 0; i < NQ; i++) {
#pragma unroll
        for (int j = i + 1; j < NQ; j++) {
            float cdl = cl[i] * cn[j] + sl[i] * sn[j];   // ls_i*cos(cs_i-cs_j)
            float sdl = sl[i] * cn[j] - cl[i] * sn[j];   // ls_i*sin(cs_i-cs_j)
            T[j][i]  = lcoef[j] * cdl + Is_suf[j];       // M[i][j] == M[j][i]
            float sij = lcoef[j] * sdl;                  // S[i][j]; S[j][i] = -sij
            w[i] += sij * v[j];  w[j] -= sij * v[i];
            z[i] += sij * vv[j]; z[j] -= sij * vv[i];
        }
    }

    // suffix sum of v[i]*w[i]; gravity gradient suffix sum
    float sufvw[NQ], G[NQ];
    {
        float acc = 0.f, accg = 0.f;
#pragma unroll
        for (int i = NQ - 1; i >= 0; i--) {
            acc  += v[i] * w[i];      sufvw[i] = acc;
            accg += gcoef[i] * sn[i]; G[i] = accg;
        }
    }

    // rhs = taus*u - Cv - G;  Cv[k] = -Vc[k]*w[k] + z[k] + sufvw[k]
    float rhs[NQ];
#pragma unroll
    for (int k = 0; k < NQ; k++) {
        float Cv = -Vc[k] * w[k] + z[k] + sufvw[k];
        rhs[k] = taus[k] * u[k] - Cv - G[k];
    }

    // ---- right-looking Cholesky, in registers; diag holds 1/sqrt(d) ----
#pragma unroll
    for (int j = 0; j < NQ; j++) {
        float rinv = __builtin_amdgcn_rsqf(T[j][j]);   // v_rsq_f32
        T[j][j] = rinv;
#pragma unroll
        for (int i = j + 1; i < NQ; i++) T[i][j] *= rinv;
#pragma unroll
        for (int k = j + 1; k < NQ; k++)
#pragma unroll
            for (int i = k; i < NQ; i++) T[i][k] -= T[i][j] * T[k][j];
    }
    // forward: L y = rhs
    float y[NQ];
#pragma unroll
    for (int i = 0; i < NQ; i++) {
        float s = rhs[i];
#pragma unroll
        for (int t = 0; t < i; t++) s -= T[i][t] * y[t];
        y[i] = s * T[i][i];
    }
    // backward: L^T x = y
    float x[NQ];
#pragma unroll
    for (int i = NQ - 1; i >= 0; i--) {
        float s = y[i];
#pragma unroll
        for (int t = i + 1; t < NQ; t++) s -= T[t][i] * x[t];
        x[i] = s * T[i][i];
    }

    float4* o4 = reinterpret_cast<float4*>(outg) + (size_t)b * 2;
    o4[0] = make_float4(x[0], x[1], x[2], x[3]);
    o4[1] = make_float4(x[4], x[5], x[6], x[7]);
}

extern "C" void kernel_launch(void* const* d_in, const int* in_sizes, int n_in,
                              void* d_out, int out_size, void* d_ws, size_t ws_size,
                              hipStream_t stream) {
    const float* q = (const float*)d_in[0];
    const float* v = (const float*)d_in[1];
    const float* u = (const float*)d_in[2];
    const float* p = (const float*)d_in[3];
    float* out = (float*)d_out;
    int B = in_sizes[0] / NQ;
    const int threads = 256;
    int blocks = (B + threads - 1) / threads;
    acrobot_kernel<<<blocks, threads, 0, stream>>>(q, v, u, p, out, B);
}

// Round 5
// 10.918 us; speedup vs baseline: 2.4726x; 1.7276x over previous
//
#include <hip/hip_runtime.h>

#define NQ 8

// ROUND 5 = NOISE A/B: byte-identical resubmission of the round-2 kernel
// (best measured: 9.85 us). R4's only change was the sincos path and it
// "cost" +9 us with no plausible mechanism -- re-measuring the R2 source
// to estimate run-to-run noise before drawing any further conclusions.

__global__ __launch_bounds__(256) void acrobot_kernel(
    const float* __restrict__ qg, const float* __restrict__ vg,
    const float* __restrict__ ug, const float* __restrict__ pg,
    float* __restrict__ outg, int B)
{
    const int b = blockIdx.x * blockDim.x + threadIdx.x;
    if (b >= B) return;

    // ---- per-sample loads first (issue early; 2 dwordx4 each, coalesced) ----
    const float4* q4 = reinterpret_cast<const float4*>(qg) + (size_t)b * 2;
    const float4* v4 = reinterpret_cast<const float4*>(vg) + (size_t)b * 2;
    const float4* u4 = reinterpret_cast<const float4*>(ug) + (size_t)b * 2;
    float4 qa = q4[0], qb = q4[1];
    float4 va = v4[0], vb = v4[1];
    float4 ua = u4[0], ub = u4[1];

    // ---- uniform params (constant indices -> s_load) ----
    float ms[NQ], ls[NQ], taus[NQ];
#pragma unroll
    for (int i = 0; i < NQ; i++) ms[i] = pg[i];
#pragma unroll
    for (int i = 0; i < NQ; i++) ls[i] = pg[NQ + i];
    const float grav = pg[2 * NQ];
#pragma unroll
    for (int i = 0; i < NQ; i++) taus[i] = pg[2 * NQ + 1 + i];

    // suffix sums: ms_suf[i] = sum_{k>=i} ms[k]; Is_suf likewise for ms*ls^2/12
    float ms_suf[NQ], Is_suf[NQ];
    {
        float accm = 0.f, acci = 0.f;
#pragma unroll
        for (int i = NQ - 1; i >= 0; i--) {
            accm += ms[i];
            acci += ms[i] * ls[i] * ls[i] * (1.0f / 12.0f);
            ms_suf[i] = accm;
            Is_suf[i] = acci;
        }
    }
    float lcoef[NQ], Dd[NQ], gcoef[NQ];
#pragma unroll
    for (int i = 0; i < NQ; i++) {
        float coefA = ms_suf[i] - 0.5f * ms[i];
        lcoef[i] = ls[i] * coefA;                       // A[i][j] = ls[i] * lcoef[j] (j = max)
        Dd[i]    = ls[i] * ls[i] * (ms_suf[i] - 0.75f * ms[i]) + Is_suf[i];
        gcoef[i] = grav * ls[i] * coefA;
    }

    float q[NQ] = {qa.x, qa.y, qa.z, qa.w, qb.x, qb.y, qb.z, qb.w};
    float v[NQ] = {va.x, va.y, va.z, va.w, vb.x, vb.y, vb.z, vb.w};
    float u[NQ] = {ua.x, ua.y, ua.z, ua.w, ub.x, ub.y, ub.z, ub.w};

    // cumsum of q; sincos of each partial sum
    float cs[NQ];
    cs[0] = q[0];
#pragma unroll
    for (int i = 1; i < NQ; i++) cs[i] = cs[i - 1] + q[i];
    float sn[NQ], cn[NQ];
#pragma unroll
    for (int i = 0; i < NQ; i++) __sincosf(cs[i], &sn[i], &cn[i]);

    // cumsum of v; vv = v .* Vc
    float Vc[NQ];
    Vc[0] = v[0];
#pragma unroll
    for (int i = 1; i < NQ; i++) Vc[i] = Vc[i - 1] + v[i];
    float vv[NQ];
#pragma unroll
    for (int i = 0; i < NQ; i++) vv[i] = v[i] * Vc[i];

    // ---- build lower triangle of M; accumulate w = S*v, z = S*vv in pair loop
    // S[i][j] = A[i][j]*sin(cs_i - cs_j), antisymmetric.
    float T[NQ][NQ];   // lower triangle only (upper elements dead -> SROA'd away)
    float w[NQ], z[NQ];
#pragma unroll
    for (int i = 0; i < NQ; i++) { w[i] = 0.f; z[i] = 0.f; T[i][i] = Dd[i]; }
#pragma unroll
    for (int i = 0; i < NQ; i++) {
#pragma unroll
        for (int j = i + 1; j < NQ; j++) {
            float a  = ls[i] * lcoef[j];               // A[i][j], max = j
            float cd = cn[i] * cn[j] + sn[i] * sn[j];  // cos(cs_i - cs_j)
            float sd = sn[i] * cn[j] - cn[i] * sn[j];  // sin(cs_i - cs_j)
            T[j][i]  = a * cd + Is_suf[j];             // M[i][j] == M[j][i]
            float sij = a * sd;                        // S[i][j]; S[j][i] = -sij
            w[i] += sij * v[j];  w[j] -= sij * v[i];
            z[i] += sij * vv[j]; z[j] -= sij * vv[i];
        }
    }

    // suffix sum of v[i]*w[i]; gravity gradient suffix sum
    float sufvw[NQ], G[NQ];
    {
        float acc = 0.f, accg = 0.f;
#pragma unroll
        for (int i = NQ - 1; i >= 0; i--) {
            acc  += v[i] * w[i];     sufvw[i] = acc;
            accg += gcoef[i] * sn[i]; G[i] = accg;
        }
    }

    // rhs = taus*u - Cv - G;  Cv[k] = -Vc[k]*w[k] + z[k] + sufvw[k]
    float rhs[NQ];
#pragma unroll
    for (int k = 0; k < NQ; k++) {
        float Cv = -Vc[k] * w[k] + z[k] + sufvw[k];
        rhs[k] = taus[k] * u[k] - Cv - G[k];
    }

    // ---- right-looking Cholesky, in registers; diag holds 1/sqrt(d) ----
#pragma unroll
    for (int j = 0; j < NQ; j++) {
        float rinv = __builtin_amdgcn_rsqf(T[j][j]);   // v_rsq_f32
        T[j][j] = rinv;
#pragma unroll
        for (int i = j + 1; i < NQ; i++) T[i][j] *= rinv;
#pragma unroll
        for (int k = j + 1; k < NQ; k++)
#pragma unroll
            for (int i = k; i < NQ; i++) T[i][k] -= T[i][j] * T[k][j];
    }
    // forward: L y = rhs
    float y[NQ];
#pragma unroll
    for (int i = 0; i < NQ; i++) {
        float s = rhs[i];
#pragma unroll
        for (int t = 0; t < i; t++) s -= T[i][t] * y[t];
        y[i] = s * T[i][i];
    }
    // backward: L^T x = y
    float x[NQ];
#pragma unroll
    for (int i = NQ - 1; i >= 0; i--) {
        float s = y[i];
#pragma unroll
        for (int t = i + 1; t < NQ; t++) s -= T[t][i] * x[t];
        x[i] = s * T[i][i];
    }

    float4* o4 = reinterpret_cast<float4*>(outg) + (size_t)b * 2;
    o4[0] = make_float4(x[0], x[1], x[2], x[3]);
    o4[1] = make_float4(x[4], x[5], x[6], x[7]);
}

extern "C" void kernel_launch(void* const* d_in, const int* in_sizes, int n_in,
                              void* d_out, int out_size, void* d_ws, size_t ws_size,
                              hipStream_t stream) {
    const float* q = (const float*)d_in[0];
    const float* v = (const float*)d_in[1];
    const float* u = (const float*)d_in[2];
    const float* p = (const float*)d_in[3];
    float* out = (float*)d_out;
    int B = in_sizes[0] / NQ;
    const int threads = 256;
    int blocks = (B + threads - 1) / threads;
    acrobot_kernel<<<blocks, threads, 0, stream>>>(q, v, u, p, out, B);
}

// Round 6
// 9.816 us; speedup vs baseline: 2.7503x; 1.1123x over previous
//
#include <hip/hip_runtime.h>

#define NQ 8

// R6: R2 structure + (a) __launch_bounds__(256,1) spill insurance,
// (b) two-sided trig prescale (9-op pair body, gravity folded to 1 fma).
// K-model: kernel ~4.2us + fixed replay OH ~6.2us; noise +-1us (R2 vs R5).

__global__ __launch_bounds__(256, 1) void acrobot_kernel(
    const float* __restrict__ qg, const float* __restrict__ vg,
    const float* __restrict__ ug, const float* __restrict__ pg,
    float* __restrict__ outg, int B)
{
    const int b = blockIdx.x * blockDim.x + threadIdx.x;
    if (b >= B) return;

    // ---- per-sample loads first (issue early; 2 dwordx4 each, coalesced) ----
    const float4* q4 = reinterpret_cast<const float4*>(qg) + (size_t)b * 2;
    const float4* v4 = reinterpret_cast<const float4*>(vg) + (size_t)b * 2;
    const float4* u4 = reinterpret_cast<const float4*>(ug) + (size_t)b * 2;
    float4 qa = q4[0], qb = q4[1];
    float4 va = v4[0], vb = v4[1];
    float4 ua = u4[0], ub = u4[1];

    // ---- uniform params (constant indices -> scalar loads) ----
    float ms[NQ], ls[NQ], taus[NQ];
#pragma unroll
    for (int i = 0; i < NQ; i++) ms[i] = pg[i];
#pragma unroll
    for (int i = 0; i < NQ; i++) ls[i] = pg[NQ + i];
    const float grav = pg[2 * NQ];
#pragma unroll
    for (int i = 0; i < NQ; i++) taus[i] = pg[2 * NQ + 1 + i];

    // suffix sums: ms_suf[i] = sum_{k>=i} ms[k]; Is_suf likewise for ms*ls^2/12
    float ms_suf[NQ], Is_suf[NQ];
    {
        float accm = 0.f, acci = 0.f;
#pragma unroll
        for (int i = NQ - 1; i >= 0; i--) {
            accm += ms[i];
            acci += ms[i] * ls[i] * ls[i] * (1.0f / 12.0f);
            ms_suf[i] = accm;
            Is_suf[i] = acci;
        }
    }
    float lcoef[NQ], Dd[NQ];
#pragma unroll
    for (int i = 0; i < NQ; i++) {
        float coefA = ms_suf[i] - 0.5f * ms[i];
        lcoef[i] = ls[i] * coefA;    // A[i][j] = ls[i] * lcoef[j]  (j = max(i,j))
        Dd[i]    = ls[i] * ls[i] * (ms_suf[i] - 0.75f * ms[i]) + Is_suf[i];
    }

    float q[NQ] = {qa.x, qa.y, qa.z, qa.w, qb.x, qb.y, qb.z, qb.w};
    float v[NQ] = {va.x, va.y, va.z, va.w, vb.x, vb.y, vb.z, vb.w};
    float u[NQ] = {ua.x, ua.y, ua.z, ua.w, ub.x, ub.y, ub.z, ub.w};

    // cumsum of q; sincos of each partial sum
    float cs[NQ];
    cs[0] = q[0];
#pragma unroll
    for (int i = 1; i < NQ; i++) cs[i] = cs[i - 1] + q[i];
    float sn[NQ], cn[NQ];
#pragma unroll
    for (int i = 0; i < NQ; i++) __sincosf(cs[i], &sn[i], &cn[i]);

    // two-sided prescale: row side by ls_i, col side by lcoef_j
    float sl[NQ], cl[NQ], sL[NQ], cL[NQ];
#pragma unroll
    for (int i = 0; i < NQ; i++) {
        sl[i] = ls[i] * sn[i];    cl[i] = ls[i] * cn[i];
        sL[i] = lcoef[i] * sn[i]; cL[i] = lcoef[i] * cn[i];
    }

    // cumsum of v; vv = v .* Vc
    float Vc[NQ];
    Vc[0] = v[0];
#pragma unroll
    for (int i = 1; i < NQ; i++) Vc[i] = Vc[i - 1] + v[i];
    float vv[NQ];
#pragma unroll
    for (int i = 0; i < NQ; i++) vv[i] = v[i] * Vc[i];

    // ---- build lower triangle of M; accumulate w = S*v, z = S*vv ----
    // pair (i<j): X   = cl_i*cL_j + sl_i*sL_j = A[i][j]*cos(cs_i-cs_j)
    //             sij = sl_i*cL_j - cl_i*sL_j = A[i][j]*sin(cs_i-cs_j)  (= S[i][j])
    float T[NQ][NQ];   // lower triangle only
    float w[NQ], z[NQ];
#pragma unroll
    for (int i = 0; i < NQ; i++) { w[i] = 0.f; z[i] = 0.f; T[i][i] = Dd[i]; }
#pragma unroll
    for (int i = 0; i < NQ; i++) {
#pragma unroll
        for (int j = i + 1; j < NQ; j++) {
            float X   = cl[i] * cL[j] + sl[i] * sL[j];
            float sij = sl[i] * cL[j] - cl[i] * sL[j];
            T[j][i] = X + Is_suf[j];               // M[i][j] == M[j][i]
            w[i] += sij * v[j];  w[j] -= sij * v[i];
            z[i] += sij * vv[j]; z[j] -= sij * vv[i];
        }
    }

    // suffix sums: v.*w ; gravity G[k] = grav * sum_{t>=k} lcoef_t*sn_t = grav*sum sL
    float sufvw[NQ], G[NQ];
    {
        float acc = 0.f, accg = 0.f;
#pragma unroll
        for (int i = NQ - 1; i >= 0; i--) {
            acc  += v[i] * w[i];   sufvw[i] = acc;
            accg += grav * sL[i];  G[i] = accg;
        }
    }

    // rhs = taus*u - Cv - G;  Cv[k] = -Vc[k]*w[k] + z[k] + sufvw[k]
    float rhs[NQ];
#pragma unroll
    for (int k = 0; k < NQ; k++) {
        float Cv = -Vc[k] * w[k] + z[k] + sufvw[k];
        rhs[k] = taus[k] * u[k] - Cv - G[k];
    }

    // ---- right-looking Cholesky, in registers; diag holds 1/sqrt(d) ----
#pragma unroll
    for (int j = 0; j < NQ; j++) {
        float rinv = __builtin_amdgcn_rsqf(T[j][j]);   // v_rsq_f32
        T[j][j] = rinv;
#pragma unroll
        for (int i = j + 1; i < NQ; i++) T[i][j] *= rinv;
#pragma unroll
        for (int k = j + 1; k < NQ; k++)
#pragma unroll
            for (int i = k; i < NQ; i++) T[i][k] -= T[i][j] * T[k][j];
    }
    // forward: L y = rhs
    float y[NQ];
#pragma unroll
    for (int i = 0; i < NQ; i++) {
        float s = rhs[i];
#pragma unroll
        for (int t = 0; t < i; t++) s -= T[i][t] * y[t];
        y[i] = s * T[i][i];
    }
    // backward: L^T x = y
    float x[NQ];
#pragma unroll
    for (int i = NQ - 1; i >= 0; i--) {
        float s = y[i];
#pragma unroll
        for (int t = i + 1; t < NQ; t++) s -= T[t][i] * x[t];
        x[i] = s * T[i][i];
    }

    float4* o4 = reinterpret_cast<float4*>(outg) + (size_t)b * 2;
    o4[0] = make_float4(x[0], x[1], x[2], x[3]);
    o4[1] = make_float4(x[4], x[5], x[6], x[7]);
}

extern "C" void kernel_launch(void* const* d_in, const int* in_sizes, int n_in,
                              void* d_out, int out_size, void* d_ws, size_t ws_size,
                              hipStream_t stream) {
    const float* q = (const float*)d_in[0];
    const float* v = (const float*)d_in[1];
    const float* u = (const float*)d_in[2];
    const float* p = (const float*)d_in[3];
    float* out = (float*)d_out;
    int B = in_sizes[0] / NQ;
    const int threads = 256;
    int blocks = (B + threads - 1) / threads;
    acrobot_kernel<<<blocks, threads, 0, stream>>>(q, v, u, p, out, B);
}